// Round 7
// baseline (82.709 us; speedup 1.0000x reference)
//
#include <hip/hip_runtime.h>
#include <hip/hip_bf16.h>

// ---------------------------------------------------------------------------
// Sizes (fixed)
// ---------------------------------------------------------------------------
#define BATCH 4
#define NN    256
#define DD    600
#define HH    256
#define MROWS (BATCH*NN)   // 1024
#define KPAD  640          // DD padded to multiple of 64
#define NFUSE 1152         // 640 (h) + 512 (LR)

typedef __attribute__((ext_vector_type(8))) short bf16x8;   // 8 bf16 (4 VGPRs)
typedef __attribute__((ext_vector_type(4))) float f32x4;

__device__ __forceinline__ void gload16(const void* g, void* l)
{
    __builtin_amdgcn_global_load_lds(
        (const __attribute__((address_space(1))) void*)g,
        (__attribute__((address_space(3))) void*)l, 16, 0, 0);
}

// counted vmcnt wait; n is compile-time after full unroll -> folds to one inst
__device__ __forceinline__ void waitcnt_vm(int n)
{
    switch (n) {
    case 0:  asm volatile("s_waitcnt vmcnt(0)"  ::: "memory"); break;
    case 4:  asm volatile("s_waitcnt vmcnt(4)"  ::: "memory"); break;
    case 8:  asm volatile("s_waitcnt vmcnt(8)"  ::: "memory"); break;
    case 12: asm volatile("s_waitcnt vmcnt(12)" ::: "memory"); break;
    default: asm volatile("s_waitcnt vmcnt(0)"  ::: "memory"); break;
    }
}

// ---------------------------------------------------------------------------
// bf16 MFMA GEMM: C = A[M,K] @ BT^T (+bias cols<biasN) (+relu), K = NK*64.
// Tile 64x64x64, 256 threads = 4 waves (2x2). Ring-4 LDS pipeline (T3/T4).
// Non-fused: WF32 -> fp32 C (cols<Nvalid); WB16 -> bf16 C; WHT -> hT retile.
// FUSEDLR:  cols<KPAD -> bf16 hb (+sT retile); cols>=KPAD -> fp32 LR at gc-KPAD.
// ---------------------------------------------------------------------------
template<bool BIAS, bool RELU, bool WF32, bool WB16, bool WHT, int NK, bool FUSEDLR>
__global__ __launch_bounds__(256) void gemm_mfma(
    const __hip_bfloat16* __restrict__ A, const __hip_bfloat16* __restrict__ BT,
    const float* __restrict__ bias,
    float* __restrict__ Cf, __hip_bfloat16* __restrict__ Cb,
    __hip_bfloat16* __restrict__ hT,
    int lda, int ldb, int ldcf, int ldcb, int Nvalid, int biasN,
    long long sA, long long sBT, long long sCf, long long sCb)
{
    __shared__ __align__(16) char lds[65536];   // ring: tile t -> A at (t&3)*8K, B at 32K+(t&3)*8K

    const int bz   = blockIdx.z;
    const int tid  = threadIdx.x;
    const int lane = tid & 63;
    const int wid  = tid >> 6;
    const int wr   = wid >> 1;
    const int wc   = wid & 1;
    const int row0 = blockIdx.y * 64;
    const int col0 = blockIdx.x * 64;

    const char* Ab = (const char*)A + (bz * sA + (long long)row0 * lda) * 2;
    const char* Bb = (const char*)BT + (bz * sBT + (long long)col0 * ldb) * 2;

    const int sr   = tid >> 3;                    // 0..31
    const int scb  = (tid & 7) * 16;              // 0..112
    const int scbs = scb ^ ((sr & 7) << 4);       // inverse source swizzle

    const char* gA0 = Ab + (long long)sr        * (lda * 2) + scbs;
    const char* gA1 = Ab + (long long)(sr + 32) * (lda * 2) + scbs;
    const char* gB0 = Bb + (long long)sr        * (ldb * 2) + scbs;
    const char* gB1 = Bb + (long long)(sr + 32) * (ldb * 2) + scbs;

    f32x4 acc[2][2] = {};

    const int fr = lane & 15;
    const int kg = (lane >> 4) * 16;
    const int xv = (fr & 7) << 4;       // read-side XOR swizzle

    auto issue = [&](int t) {
        char* bA = lds + (t & 3) * 8192;
        char* bB = lds + 32768 + (t & 3) * 8192;
        const long long off = (long long)t * 128;
        gload16(gA0 + off, bA + wid * 1024);
        gload16(gA1 + off, bA + 4096 + wid * 1024);
        gload16(gB0 + off, bB + wid * 1024);
        gload16(gB1 + off, bB + 4096 + wid * 1024);
    };

    constexpr int PRE = (NK < 3) ? NK : 3;
    #pragma unroll
    for (int p = 0; p < PRE; ++p) issue(p);

    #pragma unroll
    for (int t = 0; t < NK; ++t) {
        const int imax = (t + 2 < NK - 1) ? t + 2 : NK - 1;   // last issued tile
        waitcnt_vm(4 * (imax - t));          // tile t's 4 loads complete (per wave)
        __builtin_amdgcn_s_barrier();        // all waves' loads for tile t landed
        const char* ldsA = lds + (t & 3) * 8192;
        const char* ldsB = lds + 32768 + (t & 3) * 8192;
        #pragma unroll
        for (int ks = 0; ks < 2; ++ks) {
            const int kb = ks * 64 + kg;
            bf16x8 a0 = *(const bf16x8*)(ldsA + (wr * 32 + fr)      * 128 + (kb ^ xv));
            bf16x8 a1 = *(const bf16x8*)(ldsA + (wr * 32 + 16 + fr) * 128 + (kb ^ xv));
            bf16x8 b0 = *(const bf16x8*)(ldsB + (wc * 32 + fr)      * 128 + (kb ^ xv));
            bf16x8 b1 = *(const bf16x8*)(ldsB + (wc * 32 + 16 + fr) * 128 + (kb ^ xv));
            acc[0][0] = __builtin_amdgcn_mfma_f32_16x16x32_bf16(a0, b0, acc[0][0], 0, 0, 0);
            acc[0][1] = __builtin_amdgcn_mfma_f32_16x16x32_bf16(a0, b1, acc[0][1], 0, 0, 0);
            acc[1][0] = __builtin_amdgcn_mfma_f32_16x16x32_bf16(a1, b0, acc[1][0], 0, 0, 0);
            acc[1][1] = __builtin_amdgcn_mfma_f32_16x16x32_bf16(a1, b1, acc[1][1], 0, 0, 0);
        }
        if (t + 3 < NK) issue(t + 3);        // into buffer (t-1)&3: reads done pre-barrier
    }
    __syncthreads();                          // all LDS reads done (sT reuse below)

    // epilogue: C/D frag mapping col=lane&15, row=(lane>>4)*4+reg
    const int er = (lane >> 4) * 4;
    const int ec = lane & 15;
    __hip_bfloat16* sT = (__hip_bfloat16*)lds;   // [64][72] retile buffer

    const bool doBias = BIAS && (col0 < biasN);
    #pragma unroll
    for (int mi = 0; mi < 2; ++mi) {
        #pragma unroll
        for (int ni = 0; ni < 2; ++ni) {
            const int lr0 = wr * 32 + mi * 16 + er;
            const int lc  = wc * 32 + ni * 16 + ec;
            const int gr = row0 + lr0;
            const int gc = col0 + lc;
            const float bv = doBias ? bias[gc] : 0.f;
            #pragma unroll
            for (int r = 0; r < 4; ++r) {
                float v = acc[mi][ni][r] + bv;
                if (RELU) v = fmaxf(v, 0.f);
                const __hip_bfloat16 hv = __float2bfloat16(v);
                const long long row = gr + r;
                if (FUSEDLR) {
                    if (gc < KPAD) {
                        Cb[row * ldcb + gc] = hv;
                        sT[(lr0 + r) * 72 + lc] = hv;
                    } else {
                        Cf[row * ldcf + (gc - KPAD)] = v;
                    }
                } else {
                    if (WF32 && gc < Nvalid)
                        Cf[bz * sCf + row * ldcf + gc] = v;
                    if (WB16)
                        Cb[bz * sCb + row * ldcb + gc] = hv;
                    if (WHT)
                        sT[(lr0 + r) * 72 + lc] = hv;
                }
            }
        }
    }

    if (WHT && (!FUSEDLR || col0 < KPAD)) {
        __syncthreads();
        const int b  = row0 >> 8;
        const int i0 = row0 & 255;
        const int cc = tid >> 3;         // 0..31
        const int ch = tid & 7;          // j-chunk of 8
        #pragma unroll
        for (int p = 0; p < 2; ++p) {
            const int d = col0 + cc + p * 32;
            __align__(16) __hip_bfloat16 tmp[8];
            #pragma unroll
            for (int u = 0; u < 8; ++u)
                tmp[u] = sT[(ch * 8 + u) * 72 + cc + p * 32];
            *(float4*)&hT[((long long)b * KPAD + d) * NN + i0 + ch * 8] = *(float4*)tmp;
        }
    }
}

// ---------------------------------------------------------------------------
// Prep kernel. Unit map (blockIdx.x):
//  [0,160)      wa tiles: UTl rows 640..1151 = (W_l @ aW1p)^T  (MFMA, reg-staged)
//  [160,164)    biasLR: fb_l[640+n'] = b_l . aW1p[:,n'] + (left ? ab1[n'] : 0)
//  [164,169)    fbias base: fb_l[c<640] = (c<600 ? b_l[c] : 0)
//  [169,809)    xb = bf16(pad(feature))
//  [809,1209)   UT0 rows 0..639 = W0^T (32x32 LDS transpose)
//  [1209,1609)  UT1 rows 0..639 = W1^T
// ---------------------------------------------------------------------------
__global__ __launch_bounds__(256) void prep_kernel(
    const float* __restrict__ feature, const float* __restrict__ W0,
    const float* __restrict__ W1, const float* __restrict__ aW1,
    const float* __restrict__ b0, const float* __restrict__ b1,
    const float* __restrict__ ab1,
    __hip_bfloat16* __restrict__ xb, __hip_bfloat16* __restrict__ UT0,
    __hip_bfloat16* __restrict__ UT1, float* __restrict__ fb0,
    float* __restrict__ fb1)
{
    __shared__ __align__(16) char smem[18432];
    const int u   = blockIdx.x;
    const int tid = threadIdx.x;

    if (u < 160) {
        // ---- Wa tile: C[n'][i] = sum_d aW1[d+600p][nH0+n] * W_l[i][d] ----
        const int l  = u / 80;
        const int t  = u % 80;
        const int n0 = (t / 10) * 64;     // 0..448
        const int i0 = (t % 10) * 64;     // 0..576
        const int p  = n0 >> 8;
        const int nH0 = n0 & 255;
        const float* Wl = l ? W1 : W0;
        __hip_bfloat16* UT = l ? UT1 : UT0;

        __hip_bfloat16* At = (__hip_bfloat16*)smem;   // [64][72]
        __hip_bfloat16* Bt = At + 64 * 72;            // [64][72]

        const int lane = tid & 63, wid = tid >> 6;
        const int wr = wid >> 1, wc = wid & 1;
        const int fr = lane & 15;
        const int k8 = (lane >> 4) * 8;

        f32x4 acc[2][2] = {};

        for (int d0 = 0; d0 < 640; d0 += 64) {
            __syncthreads();
            // stage A: At[n][d] = aW1[d+600p][nH0+n]
            #pragma unroll
            for (int P = 0; P < 4; ++P) {
                const int d  = d0 + (tid >> 4) + P * 16;
                const int n4 = (tid & 15) * 4;
                float4 v = make_float4(0.f, 0.f, 0.f, 0.f);
                if (d < 600) v = *(const float4*)&aW1[(long long)(d + 600 * p) * 256 + nH0 + n4];
                const float* vf = (const float*)&v;
                #pragma unroll
                for (int j2 = 0; j2 < 4; ++j2)
                    At[(n4 + j2) * 72 + (d - d0)] = __float2bfloat16(vf[j2]);
            }
            // stage B: Bt[i][d] = W_l[i0+i][d]
            #pragma unroll
            for (int P = 0; P < 4; ++P) {
                const int li = (tid >> 4) + P * 16;
                const int d4 = (tid & 15) * 4;
                float4 v = make_float4(0.f, 0.f, 0.f, 0.f);
                if (d0 + d4 < 600) v = *(const float4*)&Wl[(long long)(i0 + li) * 600 + d0 + d4];
                __align__(8) __hip_bfloat16 o[4] = {
                    __float2bfloat16(v.x), __float2bfloat16(v.y),
                    __float2bfloat16(v.z), __float2bfloat16(v.w)};
                *(float2*)&Bt[li * 72 + d4] = *(float2*)o;
            }
            __syncthreads();
            #pragma unroll
            for (int ks = 0; ks < 2; ++ks) {
                const int kb = ks * 32 + k8;
                bf16x8 a0 = *(const bf16x8*)&At[(wr * 32 + fr)      * 72 + kb];
                bf16x8 a1 = *(const bf16x8*)&At[(wr * 32 + 16 + fr) * 72 + kb];
                bf16x8 b0r = *(const bf16x8*)&Bt[(wc * 32 + fr)      * 72 + kb];
                bf16x8 b1r = *(const bf16x8*)&Bt[(wc * 32 + 16 + fr) * 72 + kb];
                acc[0][0] = __builtin_amdgcn_mfma_f32_16x16x32_bf16(a0, b0r, acc[0][0], 0, 0, 0);
                acc[0][1] = __builtin_amdgcn_mfma_f32_16x16x32_bf16(a0, b1r, acc[0][1], 0, 0, 0);
                acc[1][0] = __builtin_amdgcn_mfma_f32_16x16x32_bf16(a1, b0r, acc[1][0], 0, 0, 0);
                acc[1][1] = __builtin_amdgcn_mfma_f32_16x16x32_bf16(a1, b1r, acc[1][1], 0, 0, 0);
            }
        }
        const int er = (lane >> 4) * 4;
        const int ec = lane & 15;
        #pragma unroll
        for (int mi = 0; mi < 2; ++mi)
            #pragma unroll
            for (int ni = 0; ni < 2; ++ni) {
                const int rr = n0 + wr * 32 + mi * 16 + er;
                const int cc = i0 + wc * 32 + ni * 16 + ec;
                #pragma unroll
                for (int r = 0; r < 4; ++r)
                    UT[(long long)(640 + rr + r) * 640 + cc] =
                        __float2bfloat16(acc[mi][ni][r]);
            }
        return;
    }
    if (u < 164) {
        // ---- biasLR ----
        const int idx = u - 160;
        const int l = idx >> 1, p = idx & 1;
        const float* bl = l ? b1 : b0;
        float* fb = l ? fb1 : fb0;
        float acc = 0.f;
        for (int d = 0; d < 600; ++d)
            acc += bl[d] * aW1[(long long)(d + 600 * p) * 256 + tid];
        fb[640 + p * 256 + tid] = acc + (p == 0 ? ab1[tid] : 0.f);
        return;
    }
    if (u < 169) {
        // ---- fbias base ----
        const int e = (u - 164) * 256 + tid;   // 0..1279
        const int l = e / 640, c = e % 640;
        float* fb = l ? fb1 : fb0;
        const float* bl = l ? b1 : b0;
        fb[c] = (c < 600) ? bl[c] : 0.f;
        return;
    }
    if (u < 809) {
        // ---- xb ----
        const int idx = ((u - 169) * 256 + tid) * 4;
        const int r = idx / KPAD, c = idx % KPAD;
        float4 v = make_float4(0.f, 0.f, 0.f, 0.f);
        if (c < DD) v = *(const float4*)&feature[r * DD + c];   // DD%4==0
        __align__(8) __hip_bfloat16 o[4] = {
            __float2bfloat16(v.x), __float2bfloat16(v.y),
            __float2bfloat16(v.z), __float2bfloat16(v.w)};
        *(float2*)&xb[idx] = *(float2*)o;
        return;
    }
    // ---- W transposes into UT rows 0..639 ----
    float (*tile)[33] = (float(*)[33])smem;
    const int t = u - 809;
    const int which = (t < 400) ? 0 : 1;
    const int tt = which ? t - 400 : t;
    const int n0 = (tt / 20) * 32;
    const int k0 = (tt % 20) * 32;
    const int tx = tid & 31, ty = tid >> 5;
    const float* Wl = which ? W1 : W0;
    #pragma unroll
    for (int r = 0; r < 4; ++r) {
        const int k = k0 + ty + r * 8;
        const int n = n0 + tx;
        float v = 0.f;
        if (k < DD && n < DD) v = Wl[k * DD + n];
        tile[ty + r * 8][tx] = v;
    }
    __syncthreads();
    __hip_bfloat16* dst = which ? UT1 : UT0;
    #pragma unroll
    for (int r = 0; r < 4; ++r) {
        const int n = n0 + ty + r * 8;
        const int k = k0 + tx;
        dst[n * KPAD + k] = __float2bfloat16(tile[tx][ty + r * 8]);
    }
}

// ---------------------------------------------------------------------------
// Attention: score + leaky_relu + mask + softmax + *adj -> att (bf16)
// Block = (b, 4 rows); thread j. 256 blocks (1/CU).
// ---------------------------------------------------------------------------
__device__ __forceinline__ void block_max4(float* v, float (*red)[4])
{
    #pragma unroll
    for (int o = 32; o > 0; o >>= 1)
        #pragma unroll
        for (int q = 0; q < 4; ++q) v[q] = fmaxf(v[q], __shfl_down(v[q], o));
    const int lane = threadIdx.x & 63, w = threadIdx.x >> 6;
    if (lane == 0) { red[w][0]=v[0]; red[w][1]=v[1]; red[w][2]=v[2]; red[w][3]=v[3]; }
    __syncthreads();
    #pragma unroll
    for (int q = 0; q < 4; ++q)
        v[q] = fmaxf(fmaxf(red[0][q], red[1][q]), fmaxf(red[2][q], red[3][q]));
    __syncthreads();
}

__device__ __forceinline__ void block_sum4(float* v, float (*red)[4])
{
    #pragma unroll
    for (int o = 32; o > 0; o >>= 1)
        #pragma unroll
        for (int q = 0; q < 4; ++q) v[q] += __shfl_down(v[q], o);
    const int lane = threadIdx.x & 63, w = threadIdx.x >> 6;
    if (lane == 0) { red[w][0]=v[0]; red[w][1]=v[1]; red[w][2]=v[2]; red[w][3]=v[3]; }
    __syncthreads();
    #pragma unroll
    for (int q = 0; q < 4; ++q)
        v[q] = red[0][q] + red[1][q] + red[2][q] + red[3][q];
    __syncthreads();
}

__global__ __launch_bounds__(256) void attn_kernel(
    const float* __restrict__ LR, const float* __restrict__ aW2,
    const float* __restrict__ ab2, const float* __restrict__ adj,
    __hip_bfloat16* __restrict__ att)
{
    __shared__ float sL[4][HH];
    __shared__ float sW[HH];
    __shared__ float red[4][4];

    const int b  = blockIdx.y;
    const int i0 = blockIdx.x * 4;
    const int j  = threadIdx.x;

    sW[j] = aW2[j];
    #pragma unroll
    for (int q = 0; q < 4; ++q)
        sL[q][j] = LR[((long long)(b * NN + i0 + q)) * 512 + j];
    __syncthreads();

    const float* rp = LR + ((long long)(b * NN + j)) * 512 + HH;
    float acc[4] = {0.f, 0.f, 0.f, 0.f};
    for (int h = 0; h < HH; h += 8) {
        const float4 ra = *(const float4*)(rp + h);
        const float4 rb = *(const float4*)(rp + h + 4);
        const float4 w0 = *(const float4*)&sW[h];
        const float4 w1 = *(const float4*)&sW[h + 4];
        #pragma unroll
        for (int q = 0; q < 4; ++q) {
            const float4 l0 = *(const float4*)&sL[q][h];
            const float4 l1 = *(const float4*)&sL[q][h + 4];
            float s = fmaxf(l0.x + ra.x, 0.f) * w0.x;
            s += fmaxf(l0.y + ra.y, 0.f) * w0.y;
            s += fmaxf(l0.z + ra.z, 0.f) * w0.z;
            s += fmaxf(l0.w + ra.w, 0.f) * w0.w;
            s += fmaxf(l1.x + rb.x, 0.f) * w1.x;
            s += fmaxf(l1.y + rb.y, 0.f) * w1.y;
            s += fmaxf(l1.z + rb.z, 0.f) * w1.z;
            s += fmaxf(l1.w + rb.w, 0.f) * w1.w;
            acc[q] += s;
        }
    }

    const float ab2v = ab2[0];
    float m[4], a[4];
    #pragma unroll
    for (int q = 0; q < 4; ++q) {
        float e = acc[q] + ab2v;
        e = (e > 0.f) ? e : 0.01f * e;                       // leaky_relu
        a[q] = adj[((long long)(b * NN + i0 + q)) * NN + j];
        m[q] = (a[q] == 0.f) ? -1e9f : e;                    // mask
    }
    float mx[4] = {m[0], m[1], m[2], m[3]};
    block_max4(mx, red);
    float p[4];
    #pragma unroll
    for (int q = 0; q < 4; ++q) p[q] = __expf(m[q] - mx[q]);
    float s[4] = {p[0], p[1], p[2], p[3]};
    block_sum4(s, red);
    #pragma unroll
    for (int q = 0; q < 4; ++q)
        att[((long long)(b * NN + i0 + q)) * NN + j] = __float2bfloat16(p[q] / s[q] * a[q]);
}

// ---------------------------------------------------------------------------
// Launch: 7 kernels (prep, then per layer: fused hLR GEMM, attn, out GEMM)
// ---------------------------------------------------------------------------
extern "C" void kernel_launch(void* const* d_in, const int* in_sizes, int n_in,
                              void* d_out, int out_size, void* d_ws, size_t ws_size,
                              hipStream_t stream)
{
    const float* feature = (const float*)d_in[0];
    const float* adj     = (const float*)d_in[1];
    const float* W0      = (const float*)d_in[2];
    const float* b0      = (const float*)d_in[3];
    const float* W1      = (const float*)d_in[4];
    const float* b1      = (const float*)d_in[5];
    const float* aW1     = (const float*)d_in[6];
    const float* ab1     = (const float*)d_in[7];
    const float* aW2     = (const float*)d_in[8];
    const float* ab2     = (const float*)d_in[9];
    float* out = (float*)d_out;

    __hip_bfloat16* bw = (__hip_bfloat16*)d_ws;
    __hip_bfloat16* xb   = bw;                        // 1024*640
    __hip_bfloat16* UT0  = xb  + MROWS * KPAD;        // 1152*640
    __hip_bfloat16* UT1  = UT0 + NFUSE * KPAD;        // 1152*640
    __hip_bfloat16* hb   = UT1 + NFUSE * KPAD;        // 1024*640
    __hip_bfloat16* hT   = hb  + MROWS * KPAD;        // 4*640*256
    __hip_bfloat16* att  = hT  + BATCH * KPAD * NN;   // 4*256*256
    float* LR  = (float*)(att + BATCH * NN * NN);     // 1024*512 fp32
    float* fb0 = LR + MROWS * 512;                    // 1152
    float* fb1 = fb0 + NFUSE;                         // 1152

    prep_kernel<<<1609, 256, 0, stream>>>(
        feature, W0, W1, aW1, b0, b1, ab1, xb, UT0, UT1, fb0, fb1);

    for (int layer = 0; layer < 2; ++layer) {
        const __hip_bfloat16* UT = layer ? UT1 : UT0;
        const float* fb          = layer ? fb1 : fb0;

        // fused: [hb | LR] = xb @ [W | Wa] + fbias ; hb bf16 + hT retile, LR fp32
        gemm_mfma<true, false, true, true, true, KPAD/64, true>
            <<<dim3(NFUSE / 64, MROWS / 64, 1), 256, 0, stream>>>(
            xb, UT, fb, LR, hb, hT,
            KPAD, KPAD, 512, KPAD, 0, NFUSE, 0, 0, 0, 0);

        // att = softmax(mask(leaky(score))) * adj   bf16
        attn_kernel<<<dim3(NN / 4, BATCH), 256, 0, stream>>>(LR, aW2, ab2, adj, att);

        // out = relu(att @ h): layer0 -> xb (bf16); layer1 -> out fp32
        if (layer == 0) {
            gemm_mfma<false, true, false, true, false, NN/64, false>
                <<<dim3(KPAD / 64, NN / 64, BATCH), 256, 0, stream>>>(
                att, hT, nullptr, nullptr, xb, nullptr,
                NN, NN, 0, KPAD, 0, 0,
                (long long)NN * NN, (long long)KPAD * NN, 0, (long long)NN * KPAD);
        } else {
            gemm_mfma<false, true, true, false, false, NN/64, false>
                <<<dim3(KPAD / 64, NN / 64, BATCH), 256, 0, stream>>>(
                att, hT, nullptr, out, nullptr, nullptr,
                NN, NN, DD, 0, DD, 0,
                (long long)NN * NN, (long long)KPAD * NN, (long long)NN * DD, 0);
        }
    }
}

// Round 8
// 67.017 us; speedup vs baseline: 1.2341x; 1.2341x over previous
//
#include <hip/hip_runtime.h>
#include <hip/hip_bf16.h>

// ---------------------------------------------------------------------------
// Sizes (fixed)
// ---------------------------------------------------------------------------
#define BATCH 4
#define NN    256
#define DD    600
#define HH    256
#define MROWS (BATCH*NN)   // 1024
#define KPAD  640          // DD padded to multiple of 64

typedef __attribute__((ext_vector_type(8))) short bf16x8;   // 8 bf16 (4 VGPRs)
typedef __attribute__((ext_vector_type(4))) float f32x4;

__device__ __forceinline__ void gload16(const void* g, void* l)
{
    __builtin_amdgcn_global_load_lds(
        (const __attribute__((address_space(1))) void*)g,
        (__attribute__((address_space(3))) void*)l, 16, 0, 0);
}

// counted vmcnt wait; n is compile-time after full unroll -> folds to one inst
__device__ __forceinline__ void waitcnt_vm(int n)
{
    switch (n) {
    case 0:  asm volatile("s_waitcnt vmcnt(0)"  ::: "memory"); break;
    case 4:  asm volatile("s_waitcnt vmcnt(4)"  ::: "memory"); break;
    case 8:  asm volatile("s_waitcnt vmcnt(8)"  ::: "memory"); break;
    case 12: asm volatile("s_waitcnt vmcnt(12)" ::: "memory"); break;
    default: asm volatile("s_waitcnt vmcnt(0)"  ::: "memory"); break;
    }
}

// ---------------------------------------------------------------------------
// bf16 MFMA GEMM: C = A[M,K] @ BT^T (+bias cols<biasN) (+relu), K = NK*64.
// Tile 64x64x64, 256 threads = 4 waves (2x2), 32x32/wave.
// Ring-4 LDS buffers (64 KB): loads for tile t+3 in flight during compute of
// tile t; counted vmcnt + raw s_barrier per K-step (T3/T4 pattern).
// XCD-chunked bijective block swizzle (T1/m204): contiguous 1/8 of grid per
// XCD -> shared operand panels stay in one XCD L2 (halves L3 re-fetch).
// WF32: fp32 C (cols<Nvalid). WB16: bf16 C (all cols).
// WHT: also write hT[b][d][j] via LDS retile (M must be 1024 = 4b x 256j).
// LDS XOR-swizzle (T2/m201): linear global_load_lds dest + inverse-swizzled
// global source + swizzled ds_read_b128.
// ---------------------------------------------------------------------------
template<bool BIAS, bool RELU, bool WF32, bool WB16, bool WHT, int NK>
__global__ __launch_bounds__(256) void gemm_mfma(
    const __hip_bfloat16* __restrict__ A, const __hip_bfloat16* __restrict__ BT,
    const float* __restrict__ bias,
    float* __restrict__ Cf, __hip_bfloat16* __restrict__ Cb,
    __hip_bfloat16* __restrict__ hT,
    int lda, int ldb, int ldcf, int ldcb, int Nvalid, int biasN,
    long long sA, long long sBT, long long sCf, long long sCb)
{
    __shared__ __align__(16) char lds[65536];   // ring: tile t -> A at (t&3)*8K, B at 32K+(t&3)*8K

    // ---- XCD-chunked bijective remap (m204) of flattened block id ----
    const int nwg = gridDim.x * gridDim.y * gridDim.z;
    int lin = blockIdx.x + gridDim.x * (blockIdx.y + gridDim.y * blockIdx.z);
    {
        const int q = nwg >> 3, r = nwg & 7;
        const int xcd = lin & 7, off = lin >> 3;
        lin = (xcd < r ? xcd * (q + 1) : r * (q + 1) + (xcd - r) * q) + off;
    }
    const int bx = lin % gridDim.x;
    const int by = (lin / gridDim.x) % gridDim.y;
    const int bz = lin / (gridDim.x * gridDim.y);

    const int tid  = threadIdx.x;
    const int lane = tid & 63;
    const int wid  = tid >> 6;
    const int wr   = wid >> 1;
    const int wc   = wid & 1;
    const int row0 = by * 64;
    const int col0 = bx * 64;

    const char* Ab = (const char*)A + (bz * sA + (long long)row0 * lda) * 2;
    const char* Bb = (const char*)BT + (bz * sBT + (long long)col0 * ldb) * 2;

    const int sr   = tid >> 3;                    // 0..31
    const int scb  = (tid & 7) * 16;              // 0..112
    const int scbs = scb ^ ((sr & 7) << 4);       // inverse source swizzle

    const char* gA0 = Ab + (long long)sr        * (lda * 2) + scbs;
    const char* gA1 = Ab + (long long)(sr + 32) * (lda * 2) + scbs;
    const char* gB0 = Bb + (long long)sr        * (ldb * 2) + scbs;
    const char* gB1 = Bb + (long long)(sr + 32) * (ldb * 2) + scbs;

    f32x4 acc[2][2] = {};

    const int fr = lane & 15;
    const int kg = (lane >> 4) * 16;
    const int xv = (fr & 7) << 4;       // read-side XOR swizzle

    auto issue = [&](int t) {
        char* bA = lds + (t & 3) * 8192;
        char* bB = lds + 32768 + (t & 3) * 8192;
        const long long off = (long long)t * 128;
        gload16(gA0 + off, bA + wid * 1024);
        gload16(gA1 + off, bA + 4096 + wid * 1024);
        gload16(gB0 + off, bB + wid * 1024);
        gload16(gB1 + off, bB + 4096 + wid * 1024);
    };

    constexpr int PRE = (NK < 3) ? NK : 3;
    #pragma unroll
    for (int p = 0; p < PRE; ++p) issue(p);

    #pragma unroll
    for (int t = 0; t < NK; ++t) {
        const int imax = (t + 2 < NK - 1) ? t + 2 : NK - 1;   // last issued tile
        waitcnt_vm(4 * (imax - t));          // tile t's 4 loads complete (per wave)
        __builtin_amdgcn_s_barrier();        // all waves' loads for tile t landed
        const char* ldsA = lds + (t & 3) * 8192;
        const char* ldsB = lds + 32768 + (t & 3) * 8192;
        #pragma unroll
        for (int ks = 0; ks < 2; ++ks) {
            const int kb = ks * 64 + kg;
            bf16x8 a0 = *(const bf16x8*)(ldsA + (wr * 32 + fr)      * 128 + (kb ^ xv));
            bf16x8 a1 = *(const bf16x8*)(ldsA + (wr * 32 + 16 + fr) * 128 + (kb ^ xv));
            bf16x8 b0 = *(const bf16x8*)(ldsB + (wc * 32 + fr)      * 128 + (kb ^ xv));
            bf16x8 b1 = *(const bf16x8*)(ldsB + (wc * 32 + 16 + fr) * 128 + (kb ^ xv));
            acc[0][0] = __builtin_amdgcn_mfma_f32_16x16x32_bf16(a0, b0, acc[0][0], 0, 0, 0);
            acc[0][1] = __builtin_amdgcn_mfma_f32_16x16x32_bf16(a0, b1, acc[0][1], 0, 0, 0);
            acc[1][0] = __builtin_amdgcn_mfma_f32_16x16x32_bf16(a1, b0, acc[1][0], 0, 0, 0);
            acc[1][1] = __builtin_amdgcn_mfma_f32_16x16x32_bf16(a1, b1, acc[1][1], 0, 0, 0);
        }
        if (t + 3 < NK) issue(t + 3);        // into buffer (t-1)&3: reads done pre-barrier
    }
    __syncthreads();                          // all LDS reads done (sT reuse below)

    // epilogue: C/D frag mapping col=lane&15, row=(lane>>4)*4+reg
    const int er = (lane >> 4) * 4;
    const int ec = lane & 15;
    __hip_bfloat16* sT = (__hip_bfloat16*)lds;   // [64][72] retile buffer

    #pragma unroll
    for (int mi = 0; mi < 2; ++mi) {
        #pragma unroll
        for (int ni = 0; ni < 2; ++ni) {
            const int lr0 = wr * 32 + mi * 16 + er;
            const int lc  = wc * 32 + ni * 16 + ec;
            const int gr = row0 + lr0;
            const int gc = col0 + lc;
            const float bv = (BIAS && gc < biasN) ? bias[gc] : 0.f;
            #pragma unroll
            for (int r = 0; r < 4; ++r) {
                float v = acc[mi][ni][r] + bv;
                if (RELU) v = fmaxf(v, 0.f);
                const __hip_bfloat16 hv = __float2bfloat16(v);
                const long long row = gr + r;
                if (WF32 && gc < Nvalid)
                    Cf[bz * sCf + row * ldcf + gc] = v;
                if (WB16)
                    Cb[bz * sCb + row * ldcb + gc] = hv;
                if (WHT)
                    sT[(lr0 + r) * 72 + lc] = hv;
            }
        }
    }

    if (WHT) {
        __syncthreads();
        const int b  = row0 >> 8;
        const int i0 = row0 & 255;
        const int cc = tid >> 3;         // 0..31
        const int ch = tid & 7;          // j-chunk of 8
        #pragma unroll
        for (int p = 0; p < 2; ++p) {
            const int d = col0 + cc + p * 32;
            __align__(16) __hip_bfloat16 tmp[8];
            #pragma unroll
            for (int u = 0; u < 8; ++u)
                tmp[u] = sT[(ch * 8 + u) * 72 + cc + p * 32];
            *(float4*)&hT[((long long)b * KPAD + d) * NN + i0 + ch * 8] = *(float4*)tmp;
        }
    }
}

// ---------------------------------------------------------------------------
// Prep: xb = bf16(pad(feature)) vectorized; W0T/W1T/aW1T via 32x32 LDS
// tile transpose (coalesced both sides) + bf16 convert.
// ---------------------------------------------------------------------------
__global__ __launch_bounds__(256) void prep_kernel(
    const float* __restrict__ feature, const float* __restrict__ W0,
    const float* __restrict__ W1, const float* __restrict__ aW1,
    __hip_bfloat16* __restrict__ xb, __hip_bfloat16* __restrict__ W0T,
    __hip_bfloat16* __restrict__ W1T, __hip_bfloat16* __restrict__ aW1T)
{
    const int bid = blockIdx.x;
    const int tid = threadIdx.x;
    if (bid < 640) {
        const int idx = (bid * 256 + tid) * 4;
        const int r = idx / KPAD, c = idx % KPAD;
        float4 v = make_float4(0.f, 0.f, 0.f, 0.f);
        if (c < DD) v = *(const float4*)&feature[r * DD + c];   // DD%4==0
        __align__(8) __hip_bfloat16 o[4] = {
            __float2bfloat16(v.x), __float2bfloat16(v.y),
            __float2bfloat16(v.z), __float2bfloat16(v.w)};
        *(float2*)&xb[idx] = *(float2*)o;
        return;
    }
    __shared__ float tile[32][33];
    const int t = bid - 640;
    const int which = (t < 400) ? 0 : (t < 800) ? 1 : 2;
    const int tt = (which == 0) ? t : (which == 1) ? t - 400 : t - 800;
    const int n0 = (tt / 20) * 32;
    const int k0 = (tt % 20) * 32;
    const int tx = tid & 31, ty = tid >> 5;
    #pragma unroll
    for (int r = 0; r < 4; ++r) {
        const int k = k0 + ty + r * 8;
        const int n = n0 + tx;
        float v = 0.f;
        if (which == 0)      { if (k < DD && n < DD) v = W0[k * DD + n]; }
        else if (which == 1) { if (k < DD && n < DD) v = W1[k * DD + n]; }
        else                 { if (k < DD) v = (n < HH) ? aW1[k * HH + n]
                                                        : aW1[(DD + k) * HH + (n - HH)]; }
        tile[ty + r * 8][tx] = v;
    }
    __syncthreads();
    __hip_bfloat16* dst = (which == 0) ? W0T : (which == 1) ? W1T : aW1T;
    #pragma unroll
    for (int r = 0; r < 4; ++r) {
        const int n = n0 + ty + r * 8;
        const int k = k0 + tx;
        dst[n * KPAD + k] = __float2bfloat16(tile[tx][ty + r * 8]);
    }
}

// ---------------------------------------------------------------------------
// Attention: score + leaky_relu + mask + softmax + *adj -> att (bf16)
// Block = (b, 4 rows); thread j. 256 blocks (1/CU). adj prefetched before
// the h-loop so its latency hides under the score compute.
// ---------------------------------------------------------------------------
__device__ __forceinline__ void block_max4(float* v, float (*red)[4])
{
    #pragma unroll
    for (int o = 32; o > 0; o >>= 1)
        #pragma unroll
        for (int q = 0; q < 4; ++q) v[q] = fmaxf(v[q], __shfl_down(v[q], o));
    const int lane = threadIdx.x & 63, w = threadIdx.x >> 6;
    if (lane == 0) { red[w][0]=v[0]; red[w][1]=v[1]; red[w][2]=v[2]; red[w][3]=v[3]; }
    __syncthreads();
    #pragma unroll
    for (int q = 0; q < 4; ++q)
        v[q] = fmaxf(fmaxf(red[0][q], red[1][q]), fmaxf(red[2][q], red[3][q]));
    __syncthreads();
}

__device__ __forceinline__ void block_sum4(float* v, float (*red)[4])
{
    #pragma unroll
    for (int o = 32; o > 0; o >>= 1)
        #pragma unroll
        for (int q = 0; q < 4; ++q) v[q] += __shfl_down(v[q], o);
    const int lane = threadIdx.x & 63, w = threadIdx.x >> 6;
    if (lane == 0) { red[w][0]=v[0]; red[w][1]=v[1]; red[w][2]=v[2]; red[w][3]=v[3]; }
    __syncthreads();
    #pragma unroll
    for (int q = 0; q < 4; ++q)
        v[q] = red[0][q] + red[1][q] + red[2][q] + red[3][q];
    __syncthreads();
}

__global__ __launch_bounds__(256) void attn_kernel(
    const float* __restrict__ LR, const float* __restrict__ aW2,
    const float* __restrict__ ab2, const float* __restrict__ adj,
    __hip_bfloat16* __restrict__ att)
{
    __shared__ float sL[4][HH];
    __shared__ float sW[HH];
    __shared__ float red[4][4];

    const int b  = blockIdx.y;
    const int i0 = blockIdx.x * 4;
    const int j  = threadIdx.x;

    // prefetch adj + ab2 early: latency hides under the 256-iter score loop
    float a[4];
    #pragma unroll
    for (int q = 0; q < 4; ++q)
        a[q] = adj[((long long)(b * NN + i0 + q)) * NN + j];
    const float ab2v = ab2[0];

    sW[j] = aW2[j];
    #pragma unroll
    for (int q = 0; q < 4; ++q)
        sL[q][j] = LR[((long long)(b * NN + i0 + q)) * 512 + j];
    __syncthreads();

    const float* rp = LR + ((long long)(b * NN + j)) * 512 + HH;
    float acc[4] = {0.f, 0.f, 0.f, 0.f};
    for (int h = 0; h < HH; h += 8) {
        const float4 ra = *(const float4*)(rp + h);
        const float4 rb = *(const float4*)(rp + h + 4);
        const float4 w0 = *(const float4*)&sW[h];
        const float4 w1 = *(const float4*)&sW[h + 4];
        #pragma unroll
        for (int q = 0; q < 4; ++q) {
            const float4 l0 = *(const float4*)&sL[q][h];
            const float4 l1 = *(const float4*)&sL[q][h + 4];
            float s = fmaxf(l0.x + ra.x, 0.f) * w0.x;
            s += fmaxf(l0.y + ra.y, 0.f) * w0.y;
            s += fmaxf(l0.z + ra.z, 0.f) * w0.z;
            s += fmaxf(l0.w + ra.w, 0.f) * w0.w;
            s += fmaxf(l1.x + rb.x, 0.f) * w1.x;
            s += fmaxf(l1.y + rb.y, 0.f) * w1.y;
            s += fmaxf(l1.z + rb.z, 0.f) * w1.z;
            s += fmaxf(l1.w + rb.w, 0.f) * w1.w;
            acc[q] += s;
        }
    }

    float m[4];
    #pragma unroll
    for (int q = 0; q < 4; ++q) {
        float e = acc[q] + ab2v;
        e = (e > 0.f) ? e : 0.01f * e;                       // leaky_relu
        m[q] = (a[q] == 0.f) ? -1e9f : e;                    // mask
    }
    float mx[4] = {m[0], m[1], m[2], m[3]};
    block_max4(mx, red);
    float p[4];
    #pragma unroll
    for (int q = 0; q < 4; ++q) p[q] = __expf(m[q] - mx[q]);
    float s[4] = {p[0], p[1], p[2], p[3]};
    block_sum4(s, red);
    #pragma unroll
    for (int q = 0; q < 4; ++q)
        att[((long long)(b * NN + i0 + q)) * NN + j] = __float2bfloat16(p[q] / s[q] * a[q]);
}

// ---------------------------------------------------------------------------
// Launch
// ---------------------------------------------------------------------------
extern "C" void kernel_launch(void* const* d_in, const int* in_sizes, int n_in,
                              void* d_out, int out_size, void* d_ws, size_t ws_size,
                              hipStream_t stream)
{
    const float* feature = (const float*)d_in[0];
    const float* adj     = (const float*)d_in[1];
    const float* W0      = (const float*)d_in[2];
    const float* b0      = (const float*)d_in[3];
    const float* W1      = (const float*)d_in[4];
    const float* b1      = (const float*)d_in[5];
    const float* aW1     = (const float*)d_in[6];
    const float* ab1     = (const float*)d_in[7];
    const float* aW2     = (const float*)d_in[8];
    const float* ab2     = (const float*)d_in[9];
    float* out = (float*)d_out;

    __hip_bfloat16* bw = (__hip_bfloat16*)d_ws;
    __hip_bfloat16* xb   = bw;                       // 1024*640
    __hip_bfloat16* W0T  = xb   + MROWS * KPAD;      // 640*640
    __hip_bfloat16* W1T  = W0T  + KPAD * KPAD;       // 640*640
    __hip_bfloat16* aW1T = W1T  + KPAD * KPAD;       // 512*640
    __hip_bfloat16* hb   = aW1T + 512 * KPAD;        // 1024*640
    __hip_bfloat16* hT   = hb   + MROWS * KPAD;      // 4*640*256
    __hip_bfloat16* att  = hT   + BATCH * KPAD * NN; // 4*256*256
    float* LR = (float*)(att + BATCH * NN * NN);     // 1024*512 fp32

    prep_kernel<<<1760, 256, 0, stream>>>(feature, W0, W1, aW1, xb, W0T, W1T, aW1T);

    for (int layer = 0; layer < 2; ++layer) {
        const __hip_bfloat16* WT = layer ? W1T : W0T;
        const float* bb          = layer ? b1 : b0;

        // hb = x @ W + b  [1024][640] bf16 ; also hT[b][d][j]
        gemm_mfma<true, false, false, true, true, KPAD/64><<<dim3(KPAD / 64, MROWS / 64, 1), 256, 0, stream>>>(
            xb, WT, bb, nullptr, hb, hT,
            KPAD, KPAD, 0, KPAD, 0, DD, 0, 0, 0, 0);

        // LR = hb @ aW1T^T (+ab1 on cols<256)   [1024][512] fp32
        gemm_mfma<true, false, true, false, false, KPAD/64><<<dim3(512 / 64, MROWS / 64, 1), 256, 0, stream>>>(
            hb, aW1T, ab1, LR, nullptr, nullptr,
            KPAD, KPAD, 512, 0, 512, HH, 0, 0, 0, 0);

        // att = softmax(mask(leaky(score))) * adj   bf16
        attn_kernel<<<dim3(NN / 4, BATCH), 256, 0, stream>>>(LR, aW2, ab2, adj, att);

        // out = relu(att @ h): layer0 -> xb (bf16); layer1 -> out fp32
        if (layer == 0) {
            gemm_mfma<false, true, false, true, false, NN/64><<<dim3(KPAD / 64, NN / 64, BATCH), 256, 0, stream>>>(
                att, hT, nullptr, nullptr, xb, nullptr,
                NN, NN, 0, KPAD, 0, 0,
                (long long)NN * NN, (long long)KPAD * NN, 0, (long long)NN * KPAD);
        } else {
            gemm_mfma<false, true, true, false, false, NN/64><<<dim3(KPAD / 64, NN / 64, BATCH), 256, 0, stream>>>(
                att, hT, nullptr, out, nullptr, nullptr,
                NN, NN, DD, 0, DD, 0,
                (long long)NN * NN, (long long)KPAD * NN, (long long)NN * DD, 0);
        }
    }
}